// Round 8
// baseline (350.141 us; speedup 1.0000x reference)
//
#include <hip/hip_runtime.h>

// RGCN: N=50000, E=600000, D=64, R=65, L=2.
// out_i = relu( sum_r mean_{j in N_r(i)} x_j@W_r + x_i@root + b ) + relu( x_i@res_W + res_b )
// Counting-sort edges by relation (block-histogram sort) and by dst. MFMA bf16
// message kernel writes RAW messages; mean scale 1/cnt(d,r) is derived per row
// position by a per-node O(deg^2) pass (scale_k) and applied in gather. This
// removes the [R][N] cnt histogram entirely (its 13MB rocclr fill was 40us and
// its random atomic/fetch granule traffic dominated setup).

constexpr int NN  = 50000;
constexpr int EE  = 600000;
constexpr int DIM = 64;
constexpr int RR  = 65;
constexpr int CHUNK = 256;                        // edges per relation-chunk
constexpr int MAXCHUNKS = EE / CHUNK + RR + 8;
constexpr int SORT_BS = 1024;                     // edges per sort block
constexpr int NSB = (EE + SORT_BS - 1) / SORT_BS; // 586
constexpr int SCAN_BS = 1024;
constexpr int SCAN_NB = (NN + SCAN_BS - 1) / SCAN_BS; // 49
constexpr int XNB = 64;                           // nodes per xform block

typedef __attribute__((ext_vector_type(8))) short short8v;
typedef __attribute__((ext_vector_type(4))) float floatx4;

__device__ inline unsigned short f2bf(float f) {
  unsigned int u = __float_as_uint(f);
  return (unsigned short)((u + 0x7fffu + ((u >> 16) & 1u)) >> 16);  // RNE
}
__device__ inline float bf2f(unsigned short v) {
  return __uint_as_float(((unsigned int)v) << 16);
}

// ---------------- setup (layer-invariant, rebuilt every launch) ----------------

__global__ __launch_bounds__(256) void zero_k(int* __restrict__ p, int n) {
  const int i = blockIdx.x * 256 + threadIdx.x;
  if (i < n) p[i] = 0;
}

// Fused: deg atomics (200 KB, L2-resident) + per-block LDS type histogram.
__global__ __launch_bounds__(512) void hist2_k(const int* __restrict__ dst,
                                               const int* __restrict__ et,
                                               int* __restrict__ deg,
                                               int* __restrict__ bhist, int E) {
  __shared__ int lh[RR];
  if (threadIdx.x < RR) lh[threadIdx.x] = 0;
  __syncthreads();
  const int base = blockIdx.x * SORT_BS;
#pragma unroll
  for (int it = 0; it < SORT_BS / 512; ++it) {
    const int e = base + it * 512 + threadIdx.x;
    if (e < E) {
      atomicAdd(&deg[dst[e]], 1);     // 50k addrs, ~12 avg contention
      atomicAdd(&lh[et[e]], 1);       // LDS
    }
  }
  __syncthreads();
  if (threadIdx.x < RR) bhist[blockIdx.x * RR + threadIdx.x] = lh[threadIdx.x];
}

// ---- parallel exclusive scan of deg[NN] -> rowptr, poscur ----

__global__ __launch_bounds__(1024) void scan1_k(const int* __restrict__ deg,
                                                int* __restrict__ bsum) {
  __shared__ int s[SCAN_BS];
  const int idx = blockIdx.x * SCAN_BS + threadIdx.x;
  s[threadIdx.x] = (idx < NN) ? deg[idx] : 0;
  __syncthreads();
  for (int off = SCAN_BS / 2; off > 0; off >>= 1) {
    if (threadIdx.x < off) s[threadIdx.x] += s[threadIdx.x + off];
    __syncthreads();
  }
  if (threadIdx.x == 0) bsum[blockIdx.x] = s[0];
}

__global__ __launch_bounds__(64) void scan2_k(int* __restrict__ bsum) {
  if (threadIdx.x == 0) {
    int run = 0;
    for (int b = 0; b < SCAN_NB; ++b) { const int v = bsum[b]; bsum[b] = run; run += v; }
  }
}

__global__ __launch_bounds__(1024) void scan3_k(const int* __restrict__ deg,
                                                const int* __restrict__ bsum,
                                                int* __restrict__ rowptr,
                                                int* __restrict__ poscur) {
  __shared__ int s[SCAN_BS];
  const int t = threadIdx.x;
  const int idx = blockIdx.x * SCAN_BS + t;
  const int v = (idx < NN) ? deg[idx] : 0;
  s[t] = v;
  __syncthreads();
  for (int off = 1; off < SCAN_BS; off <<= 1) {  // Hillis-Steele inclusive
    const int u = (t >= off) ? s[t - off] : 0;
    __syncthreads();
    s[t] += u;
    __syncthreads();
  }
  const int excl = bsum[blockIdx.x] + s[t] - v;
  if (idx < NN) { rowptr[idx] = excl; poscur[idx] = excl; }
  if (idx == NN - 1) rowptr[NN] = EE;
}

__global__ __launch_bounds__(128) void scan_type_k(const int* __restrict__ bhist,
                                                   int* __restrict__ boff,
                                                   int4* __restrict__ chunkArr,
                                                   int* __restrict__ nchunks) {
  __shared__ int total[RR], tptr[RR + 1], chbase[RR + 1];
  const int t = threadIdx.x;
  if (t < RR) {
    int s = 0;
    for (int b = 0; b < NSB; ++b) s += bhist[b * RR + t];
    total[t] = s;
  }
  __syncthreads();
  if (t == 0) {
    int run = 0, crun = 0;
    for (int r = 0; r < RR; ++r) {
      tptr[r] = run;   run  += total[r];
      chbase[r] = crun; crun += (total[r] + CHUNK - 1) / CHUNK;
    }
    tptr[RR] = run; chbase[RR] = crun;
    *nchunks = crun;
  }
  __syncthreads();
  if (t < RR) {
    int run = tptr[t];
    for (int b = 0; b < NSB; ++b) { boff[b * RR + t] = run; run += bhist[b * RR + t]; }
    const int nc = (total[t] + CHUNK - 1) / CHUNK;
    for (int i = 0; i < nc; ++i) {
      const int beg = tptr[t] + i * CHUNK;
      chunkArr[chbase[t] + i] = make_int4(beg, min(beg + CHUNK, tptr[t] + total[t]), t, 0);
    }
  }
}

// Type-sorted slot q (LDS counter) + dst-sorted slot p (global atomic).
// Writes osrc/opos by q, relation by p. No cnt lookups.
__global__ __launch_bounds__(512) void scatter2_k(const int* __restrict__ src,
                                                  const int* __restrict__ dst,
                                                  const int* __restrict__ et,
                                                  const int* __restrict__ boff,
                                                  int* __restrict__ poscur,
                                                  int* __restrict__ osrc,
                                                  int* __restrict__ opos,
                                                  int* __restrict__ orel, int E) {
  __shared__ int cur[RR];
  if (threadIdx.x < RR) cur[threadIdx.x] = boff[blockIdx.x * RR + threadIdx.x];
  __syncthreads();
  const int base = blockIdx.x * SORT_BS;
#pragma unroll
  for (int it = 0; it < SORT_BS / 512; ++it) {
    const int e = base + it * 512 + threadIdx.x;
    if (e < E) {
      const int s = src[e], d = dst[e], r = et[e];
      const int q = atomicAdd(&cur[r], 1);       // LDS atomic, block-local
      const int p = atomicAdd(&poscur[d], 1);    // global, ~12 avg contention
      osrc[q] = s;
      opos[q] = p;
      orel[p] = r;                               // write-back cached, no granule blowup
    }
  }
}

// Per-node O(deg^2): sc[p] = 1 / #{p2 in row : orel[p2]==orel[p]}  (== 1/cnt[d,r]).
__global__ __launch_bounds__(256) void scale_k(const int* __restrict__ rowptr,
                                               const int* __restrict__ orel,
                                               float* __restrict__ sc, int N) {
  const int n = blockIdx.x * 256 + threadIdx.x;
  if (n >= N) return;
  const int jb = rowptr[n], je = rowptr[n + 1];
  for (int j1 = jb; j1 < je; ++j1) {
    const int r1 = orel[j1];
    int c = 0;
    for (int j2 = jb; j2 < je; ++j2) c += (orel[j2] == r1) ? 1 : 0;
    sc[j1] = 1.0f / (float)c;
  }
}

// ---------------- W conversion (once, both layers) ----------------

// W[l][r][k][c] f32 -> WT[l*R+r][c][k] bf16 (transposed).
__global__ __launch_bounds__(256) void cvtw_k(const float* __restrict__ W,
                                              unsigned short* __restrict__ WT) {
  const int tid = blockIdx.x * 256 + threadIdx.x;     // one float4 per thread
  const int total4 = 2 * RR * DIM * DIM / 4;          // 133120
  if (tid >= total4) return;
  const int base = tid * 4;
  const int mat = base >> 12;
  const int rem = base & 4095;
  const int k = rem >> 6, c0 = rem & 63;
  const float4 v = *reinterpret_cast<const float4*>(W + base);
  unsigned short* o = WT + (size_t)mat * 4096;
  o[(c0 + 0) * 64 + k] = f2bf(v.x);
  o[(c0 + 1) * 64 + k] = f2bf(v.y);
  o[(c0 + 2) * 64 + k] = f2bf(v.z);
  o[(c0 + 3) * 64 + k] = f2bf(v.w);
}

// ---------------- per-layer kernels ----------------

// MFMA message kernel: one block per 256-edge relation-chunk, 4 waves x 64 edges.
// Writes RAW (unscaled) bf16 messages.
__global__ __launch_bounds__(256) void msgm_k(const unsigned short* __restrict__ hbf,
                                              const int* __restrict__ osrc,
                                              const int* __restrict__ opos,
                                              const unsigned short* __restrict__ WT,
                                              const int4* __restrict__ chunkArr,
                                              const int* __restrict__ nchunks,
                                              unsigned short* __restrict__ m) {
  const int ci = blockIdx.x;
  if (ci >= *nchunks) return;
  const int4 c = chunkArr[ci];
  const int beg = c.x, end = c.y, rel = c.z;

  __shared__ unsigned short Wl[DIM][72];   // +8 pad
  {
    const float4* s4 = reinterpret_cast<const float4*>(WT + (size_t)rel * 4096);
#pragma unroll
    for (int it = 0; it < 2; ++it) {
      const int seg = threadIdx.x + it * 256;   // 512 x 16B segments
      const int row = seg >> 3, s8 = seg & 7;
      *reinterpret_cast<float4*>(&Wl[row][s8 * 8]) = s4[seg];
    }
  }
  __syncthreads();

  const int w  = threadIdx.x >> 6;
  const int l  = threadIdx.x & 63;
  const int lr = l & 15, lq = l >> 4;

  const int ebase = beg + w * 64;
  if (ebase >= end) return;                // no barriers after this point

  short8v a[4][2];
#pragma unroll
  for (int ct = 0; ct < 4; ++ct)
#pragma unroll
    for (int kk = 0; kk < 2; ++kk)
      a[ct][kk] = *reinterpret_cast<const short8v*>(&Wl[ct * 16 + lr][kk * 32 + lq * 8]);

  short8v b[4][2];
  int eidx[4];
#pragma unroll
  for (int et = 0; et < 4; ++et) {
    eidx[et] = ebase + et * 16 + lr;
    const int e = min(eidx[et], end - 1);  // clamp (safe dup, store guarded)
    const int s = osrc[e];
    const unsigned short* hp = hbf + (size_t)s * DIM;
    b[et][0] = *reinterpret_cast<const short8v*>(hp + lq * 8);
    b[et][1] = *reinterpret_cast<const short8v*>(hp + 32 + lq * 8);
  }

  floatx4 acc[4][4];
#pragma unroll
  for (int ct = 0; ct < 4; ++ct)
#pragma unroll
    for (int et = 0; et < 4; ++et)
      acc[ct][et] = (floatx4){0.f, 0.f, 0.f, 0.f};

#pragma unroll
  for (int kk = 0; kk < 2; ++kk)
#pragma unroll
    for (int ct = 0; ct < 4; ++ct)
#pragma unroll
      for (int et = 0; et < 4; ++et)
        acc[ct][et] = __builtin_amdgcn_mfma_f32_16x16x32_bf16(a[ct][kk], b[et][kk],
                                                              acc[ct][et], 0, 0, 0);

#pragma unroll
  for (int et = 0; et < 4; ++et) {
    const int e = eidx[et];
    if (e < end) {
      unsigned short* op = m + (size_t)opos[e] * DIM;
#pragma unroll
      for (int ct = 0; ct < 4; ++ct) {
        ushort4 o;
        o.x = f2bf(acc[ct][et][0]);
        o.y = f2bf(acc[ct][et][1]);
        o.z = f2bf(acc[ct][et][2]);
        o.w = f2bf(acc[ct][et][3]);
        *reinterpret_cast<ushort4*>(op + ct * 16 + lq * 4) = o;
      }
    }
  }
}

// Dense node transform: rt = h@root + b, rs = relu(h@rw + rb); also emits h as bf16.
__global__ __launch_bounds__(256) void xform_k(const float* __restrict__ h,
                                               const float* __restrict__ root,
                                               const float* __restrict__ bias,
                                               const float* __restrict__ rw,
                                               const float* __restrict__ rb,
                                               float* __restrict__ rt,
                                               float* __restrict__ rs,
                                               unsigned short* __restrict__ hbf, int N) {
  __shared__ float Wl0[DIM * DIM];
  __shared__ float Wl1[DIM * DIM];
  __shared__ float xs[XNB][68];
#pragma unroll
  for (int i = 0; i < 4; ++i) {
    reinterpret_cast<float4*>(Wl0)[threadIdx.x + i * 256] =
        reinterpret_cast<const float4*>(root)[threadIdx.x + i * 256];
    reinterpret_cast<float4*>(Wl1)[threadIdx.x + i * 256] =
        reinterpret_cast<const float4*>(rw)[threadIdx.x + i * 256];
  }

  const int g = threadIdx.x >> 4, li = threadIdx.x & 15;
  const int base = blockIdx.x * XNB;
#pragma unroll
  for (int r = 0; r < 4; ++r) {
    const int n = base + g * 4 + r;
    float4 v = make_float4(0.f, 0.f, 0.f, 0.f);
    if (n < N) v = *reinterpret_cast<const float4*>(h + (size_t)n * DIM + li * 4);
    *reinterpret_cast<float4*>(&xs[g * 4 + r][li * 4]) = v;
  }
  __syncthreads();

  if (hbf != nullptr) {
#pragma unroll
    for (int r = 0; r < 4; ++r) {
      const int n = base + g * 4 + r;
      if (n < N) {
        const float4 v = *reinterpret_cast<const float4*>(&xs[g * 4 + r][li * 4]);
        ushort4 o;
        o.x = f2bf(v.x); o.y = f2bf(v.y); o.z = f2bf(v.z); o.w = f2bf(v.w);
        *reinterpret_cast<ushort4*>(hbf + (size_t)n * DIM + li * 4) = o;
      }
    }
  }

  float aR[4][4], aS[4][4];
#pragma unroll
  for (int r = 0; r < 4; ++r)
#pragma unroll
    for (int q = 0; q < 4; ++q) { aR[r][q] = 0.f; aS[r][q] = 0.f; }

#pragma unroll 4
  for (int k = 0; k < DIM; ++k) {
    const float4 wr = *reinterpret_cast<const float4*>(&Wl0[k * DIM + li * 4]);
    const float4 wv = *reinterpret_cast<const float4*>(&Wl1[k * DIM + li * 4]);
#pragma unroll
    for (int r = 0; r < 4; ++r) {
      const float xv = xs[g * 4 + r][k];
      aR[r][0] += xv * wr.x; aR[r][1] += xv * wr.y; aR[r][2] += xv * wr.z; aR[r][3] += xv * wr.w;
      aS[r][0] += xv * wv.x; aS[r][1] += xv * wv.y; aS[r][2] += xv * wv.z; aS[r][3] += xv * wv.w;
    }
  }

  const float4 bv = reinterpret_cast<const float4*>(bias)[li];
  const float4 cv = reinterpret_cast<const float4*>(rb)[li];
#pragma unroll
  for (int r = 0; r < 4; ++r) {
    const int n = base + g * 4 + r;
    if (n < N) {
      *reinterpret_cast<float4*>(rt + (size_t)n * DIM + li * 4) =
          make_float4(aR[r][0] + bv.x, aR[r][1] + bv.y, aR[r][2] + bv.z, aR[r][3] + bv.w);
      *reinterpret_cast<float4*>(rs + (size_t)n * DIM + li * 4) =
          make_float4(fmaxf(aS[r][0] + cv.x, 0.f), fmaxf(aS[r][1] + cv.y, 0.f),
                      fmaxf(aS[r][2] + cv.z, 0.f), fmaxf(aS[r][3] + cv.w, 0.f));
    }
  }
}

// Streaming epilogue: hout = relu(sum_j sc[j]*msg[j] + rt) + rs. 4x unrolled.
__global__ __launch_bounds__(256) void gather3_k(const unsigned short* __restrict__ m,
                                                 const float* __restrict__ sc,
                                                 const int* __restrict__ rowptr,
                                                 const float* __restrict__ rt,
                                                 const float* __restrict__ rs,
                                                 float* __restrict__ hout, int N) {
  const int g = threadIdx.x >> 4, li = threadIdx.x & 15;
  const int n = blockIdx.x * 16 + g;
  if (n >= N) return;

  float a0 = 0.f, a1 = 0.f, a2 = 0.f, a3 = 0.f;
  const int jb = rowptr[n], je = rowptr[n + 1];
  int j = jb;
  for (; j + 4 <= je; j += 4) {
    const float c0 = sc[j + 0], c1 = sc[j + 1], c2 = sc[j + 2], c3 = sc[j + 3];
    const ushort4 v0 = *reinterpret_cast<const ushort4*>(m + (size_t)(j + 0) * DIM + li * 4);
    const ushort4 v1 = *reinterpret_cast<const ushort4*>(m + (size_t)(j + 1) * DIM + li * 4);
    const ushort4 v2 = *reinterpret_cast<const ushort4*>(m + (size_t)(j + 2) * DIM + li * 4);
    const ushort4 v3 = *reinterpret_cast<const ushort4*>(m + (size_t)(j + 3) * DIM + li * 4);
    a0 += c0 * bf2f(v0.x) + c1 * bf2f(v1.x) + c2 * bf2f(v2.x) + c3 * bf2f(v3.x);
    a1 += c0 * bf2f(v0.y) + c1 * bf2f(v1.y) + c2 * bf2f(v2.y) + c3 * bf2f(v3.y);
    a2 += c0 * bf2f(v0.z) + c1 * bf2f(v1.z) + c2 * bf2f(v2.z) + c3 * bf2f(v3.z);
    a3 += c0 * bf2f(v0.w) + c1 * bf2f(v1.w) + c2 * bf2f(v2.w) + c3 * bf2f(v3.w);
  }
  for (; j < je; ++j) {
    const float cc = sc[j];
    const ushort4 v = *reinterpret_cast<const ushort4*>(m + (size_t)j * DIM + li * 4);
    a0 += cc * bf2f(v.x); a1 += cc * bf2f(v.y); a2 += cc * bf2f(v.z); a3 += cc * bf2f(v.w);
  }

  const float4 t = *reinterpret_cast<const float4*>(rt + (size_t)n * DIM + li * 4);
  const float4 s = *reinterpret_cast<const float4*>(rs + (size_t)n * DIM + li * 4);
  *reinterpret_cast<float4*>(hout + (size_t)n * DIM + li * 4) =
      make_float4(fmaxf(a0 + t.x, 0.f) + s.x, fmaxf(a1 + t.y, 0.f) + s.y,
                  fmaxf(a2 + t.z, 0.f) + s.z, fmaxf(a3 + t.w, 0.f) + s.w);
}

// ---------------- last-resort fallback (float atomics, self-contained) ----------------

__global__ __launch_bounds__(256) void count_k(const int* __restrict__ dst,
                                               const int* __restrict__ et,
                                               int* __restrict__ cnt, int E) {
  int e = blockIdx.x * 256 + threadIdx.x;
  if (e < E) atomicAdd(&cnt[dst[e] * RR + et[e]], 1);
}

__global__ __launch_bounds__(256) void edge_k(const float* __restrict__ h,
                                              const int* __restrict__ src,
                                              const int* __restrict__ dst,
                                              const int* __restrict__ et,
                                              const float* __restrict__ W,
                                              const int* __restrict__ cnt,
                                              float* __restrict__ accum, int E) {
  __shared__ float xs[16][68];
  const int g = threadIdx.x >> 4, li = threadIdx.x & 15;
  const int e = blockIdx.x * 16 + g;
  if (e >= E) return;
  const int s = src[e], d = dst[e], t = et[e];
  *reinterpret_cast<float4*>(&xs[g][li * 4]) =
      *reinterpret_cast<const float4*>(h + (size_t)s * DIM + li * 4);
  const float* Wt = W + (size_t)t * (DIM * DIM) + li * 4;
  float a0 = 0.f, a1 = 0.f, a2 = 0.f, a3 = 0.f;
#pragma unroll 8
  for (int k = 0; k < DIM; ++k) {
    const float xd = xs[g][k];
    const float4 w = *reinterpret_cast<const float4*>(Wt + k * DIM);
    a0 += xd * w.x; a1 += xd * w.y; a2 += xd * w.z; a3 += xd * w.w;
  }
  const float sc = 1.0f / (float)cnt[d * RR + t];
  float* o = accum + (size_t)d * DIM + li * 4;
  unsafeAtomicAdd(o + 0, a0 * sc);
  unsafeAtomicAdd(o + 1, a1 * sc);
  unsafeAtomicAdd(o + 2, a2 * sc);
  unsafeAtomicAdd(o + 3, a3 * sc);
}

__global__ __launch_bounds__(256) void node_k(const float* __restrict__ h,
                                              const float* __restrict__ root,
                                              const float* __restrict__ bias,
                                              const float* __restrict__ rw,
                                              const float* __restrict__ rb,
                                              float* __restrict__ io, int N) {
  __shared__ float xs[16][68];
  const int g = threadIdx.x >> 4, li = threadIdx.x & 15;
  const int n = blockIdx.x * 16 + g;
  if (n >= N) return;
  *reinterpret_cast<float4*>(&xs[g][li * 4]) =
      *reinterpret_cast<const float4*>(h + (size_t)n * DIM + li * 4);
  float r0 = 0.f, r1 = 0.f, r2 = 0.f, r3 = 0.f;
  float s0 = 0.f, s1 = 0.f, s2 = 0.f, s3 = 0.f;
#pragma unroll 8
  for (int k = 0; k < DIM; ++k) {
    const float hd = xs[g][k];
    const float4 w = *reinterpret_cast<const float4*>(root + k * DIM + li * 4);
    const float4 v = *reinterpret_cast<const float4*>(rw + k * DIM + li * 4);
    r0 += hd * w.x; r1 += hd * w.y; r2 += hd * w.z; r3 += hd * w.w;
    s0 += hd * v.x; s1 += hd * v.y; s2 += hd * v.z; s3 += hd * v.w;
  }
  float* o = io + (size_t)n * DIM + li * 4;
  const float4 acc = *reinterpret_cast<const float4*>(o);
  const float4 b = *reinterpret_cast<const float4*>(bias + li * 4);
  const float4 c = *reinterpret_cast<const float4*>(rb + li * 4);
  float o0 = fmaxf(acc.x + r0 + b.x, 0.f) + fmaxf(s0 + c.x, 0.f);
  float o1 = fmaxf(acc.y + r1 + b.y, 0.f) + fmaxf(s1 + c.y, 0.f);
  float o2 = fmaxf(acc.z + r2 + b.z, 0.f) + fmaxf(s2 + c.z, 0.f);
  float o3 = fmaxf(acc.w + r3 + b.w, 0.f) + fmaxf(s3 + c.w, 0.f);
  *reinterpret_cast<float4*>(o) = make_float4(o0, o1, o2, o3);
}

// ---------------- host ----------------

extern "C" void kernel_launch(void* const* d_in, const int* in_sizes, int n_in,
                              void* d_out, int out_size, void* d_ws, size_t ws_size,
                              hipStream_t stream) {
  const float* x    = (const float*)d_in[0];
  const int*   ei   = (const int*)d_in[1];
  const int*   et   = (const int*)d_in[2];
  const float* W    = (const float*)d_in[3];
  const float* root = (const float*)d_in[4];
  const float* bias = (const float*)d_in[5];
  const float* resW = (const float*)d_in[6];
  const float* resb = (const float*)d_in[7];
  float* out = (float*)d_out;

  const int* src = ei;
  const int* dstp = ei + EE;

  char* ws = (char*)d_ws;
  size_t off = 0;
  auto take = [&](size_t bytes) -> void* {
    void* p = ws + off;
    off = (off + bytes + 255) & ~(size_t)255;
    return p;
  };
  unsigned short* m = (unsigned short*)take((size_t)EE * DIM * sizeof(unsigned short));
  float* h1      = (float*)take((size_t)NN * DIM * sizeof(float));
  int* deg       = (int*)take((size_t)NN * sizeof(int));
  int* rowptr    = (int*)take((size_t)(NN + 1) * sizeof(int));
  int* poscur    = (int*)take((size_t)NN * sizeof(int));
  int* bhist     = (int*)take((size_t)NSB * RR * sizeof(int));
  int* boff      = (int*)take((size_t)NSB * RR * sizeof(int));
  int* bsum      = (int*)take((size_t)SCAN_NB * sizeof(int));
  int* osrc      = (int*)take((size_t)EE * sizeof(int));
  int* opos      = (int*)take((size_t)EE * sizeof(int));
  int* orel      = (int*)take((size_t)EE * sizeof(int));
  float* sc      = (float*)take((size_t)EE * sizeof(float));
  int4* chunkArr = (int4*)take((size_t)MAXCHUNKS * sizeof(int4));
  int* nchunks   = (int*)take(256);
  float* rt      = (float*)take((size_t)NN * DIM * sizeof(float));
  float* rs      = (float*)take((size_t)NN * DIM * sizeof(float));
  unsigned short* hbf = (unsigned short*)take((size_t)NN * DIM * sizeof(unsigned short));
  unsigned short* wbt = (unsigned short*)take((size_t)2 * RR * DIM * DIM * sizeof(unsigned short));
  const size_t main_off = off;

  if (main_off <= ws_size) {
    // ---- sorted MFMA path (no rocclr fills anywhere) ----
    zero_k<<<(NN + 255) / 256, 256, 0, stream>>>(deg, NN);
    hist2_k<<<NSB, 512, 0, stream>>>(dstp, et, deg, bhist, EE);
    scan1_k<<<SCAN_NB, 1024, 0, stream>>>(deg, bsum);
    scan2_k<<<1, 64, 0, stream>>>(bsum);
    scan3_k<<<SCAN_NB, 1024, 0, stream>>>(deg, bsum, rowptr, poscur);
    scan_type_k<<<1, 128, 0, stream>>>(bhist, boff, chunkArr, nchunks);
    scatter2_k<<<NSB, 512, 0, stream>>>(src, dstp, et, boff, poscur,
                                        osrc, opos, orel, EE);
    scale_k<<<(NN + 255) / 256, 256, 0, stream>>>(rowptr, orel, sc, NN);
    cvtw_k<<<(2 * RR * DIM * DIM / 4 + 255) / 256, 256, 0, stream>>>(W, wbt);

    const int XG = (NN + XNB - 1) / XNB;
    // layer 0: x -> h1
    xform_k<<<XG, 256, 0, stream>>>(x, root, bias, resW, resb, rt, rs, hbf, NN);
    msgm_k<<<MAXCHUNKS, 256, 0, stream>>>(hbf, osrc, opos, wbt, chunkArr, nchunks, m);
    gather3_k<<<(NN + 15) / 16, 256, 0, stream>>>(m, sc, rowptr, rt, rs, h1, NN);
    // layer 1: h1 -> out
    xform_k<<<XG, 256, 0, stream>>>(h1, root + DIM * DIM, bias + DIM,
                                    resW + DIM * DIM, resb + DIM, rt, rs, hbf, NN);
    msgm_k<<<MAXCHUNKS, 256, 0, stream>>>(hbf, osrc, opos,
                                          wbt + (size_t)RR * DIM * DIM, chunkArr, nchunks, m);
    gather3_k<<<(NN + 15) / 16, 256, 0, stream>>>(m, sc, rowptr, rt, rs, out, NN);
  } else {
    // ---- fallback: atomic path (needs only 25.8 MB) ----
    int* fcnt = (int*)ws;
    float* fh1 = (float*)(ws + (size_t)NN * RR * sizeof(int));
    hipMemsetAsync(fcnt, 0, (size_t)NN * RR * sizeof(int), stream);
    hipMemsetAsync(fh1, 0, (size_t)NN * DIM * sizeof(float), stream);
    hipMemsetAsync(out, 0, (size_t)NN * DIM * sizeof(float), stream);
    count_k<<<(EE + 255) / 256, 256, 0, stream>>>(dstp, et, fcnt, EE);
    edge_k<<<(EE + 15) / 16, 256, 0, stream>>>(x, src, dstp, et, W, fcnt, fh1, EE);
    node_k<<<(NN + 15) / 16, 256, 0, stream>>>(x, root, bias, resW, resb, fh1, NN);
    edge_k<<<(EE + 15) / 16, 256, 0, stream>>>(fh1, src, dstp, et,
                                               W + (size_t)RR * DIM * DIM, fcnt, out, EE);
    node_k<<<(NN + 15) / 16, 256, 0, stream>>>(fh1, root + DIM * DIM, bias + DIM,
                                               resW + DIM * DIM, resb + DIM, out, NN);
  }
}

// Round 9
// 246.255 us; speedup vs baseline: 1.4219x; 1.4219x over previous
//
#include <hip/hip_runtime.h>

// RGCN: N=50000, E=600000, D=64, R=65, L=2.
// out_i = relu( sum_r mean_{j in N_r(i)} x_j@W_r + x_i@root + b ) + relu( x_i@res_W + res_b )
// Round-7 cnt-based counting-sort pipeline (relation-sort for MFMA W reuse,
// dst-sort for CSR gather; oscale=1/cnt fetched in scatter, applied in msgm)
// with two measured fixes: custom int4 zero kernel for the 13MB cnt (rocclr
// fill was 40us @ 322GB/s) and a parallel two-stage type-scan (single-block
// serial scan was 31-62us latency-bound).

constexpr int NN  = 50000;
constexpr int EE  = 600000;
constexpr int DIM = 64;
constexpr int RR  = 65;
constexpr int CHUNK = 256;                        // edges per relation-chunk
constexpr int MAXCHUNKS = EE / CHUNK + RR + 8;
constexpr int SORT_BS = 2048;                     // edges per sort block
constexpr int NSB = (EE + SORT_BS - 1) / SORT_BS; // 293
constexpr int SCAN_BS = 1024;
constexpr int SCAN_NB = (NN + SCAN_BS - 1) / SCAN_BS; // 49
constexpr int XNB = 64;                           // nodes per xform block

typedef __attribute__((ext_vector_type(8))) short short8v;
typedef __attribute__((ext_vector_type(4))) float floatx4;

__device__ inline unsigned short f2bf(float f) {
  unsigned int u = __float_as_uint(f);
  return (unsigned short)((u + 0x7fffu + ((u >> 16) & 1u)) >> 16);  // RNE
}
__device__ inline float bf2f(unsigned short v) {
  return __uint_as_float(((unsigned int)v) << 16);
}

// ---------------- setup (layer-invariant, rebuilt every launch) ----------------

__global__ __launch_bounds__(256) void zero4_k(int4* __restrict__ p, int n4) {
  const int i = blockIdx.x * 256 + threadIdx.x;
  if (i < n4) p[i] = make_int4(0, 0, 0, 0);
}

// One thread per edge: max outstanding atomics. cnt layout [R][N] (transposed).
__global__ __launch_bounds__(512) void cnt_k(const int* __restrict__ dst,
                                             const int* __restrict__ et,
                                             int* __restrict__ cnt, int E) {
  const int e = blockIdx.x * 512 + threadIdx.x;
  if (e < E) atomicAdd(&cnt[et[e] * NN + dst[e]], 1);
}

// Per-sort-block 65-bin type histogram (LDS only).
__global__ __launch_bounds__(512) void bhist_k(const int* __restrict__ et,
                                               int* __restrict__ bhist, int E) {
  __shared__ int lh[RR];
  if (threadIdx.x < RR) lh[threadIdx.x] = 0;
  __syncthreads();
  const int base = blockIdx.x * SORT_BS;
#pragma unroll
  for (int it = 0; it < SORT_BS / 512; ++it) {
    const int e = base + it * 512 + threadIdx.x;
    if (e < E) atomicAdd(&lh[et[e]], 1);
  }
  __syncthreads();
  if (threadIdx.x < RR) bhist[blockIdx.x * RR + threadIdx.x] = lh[threadIdx.x];
}

// ---- parallel exclusive scan: deg derived from cnt (coalesced over [R][N]) ----

__global__ __launch_bounds__(1024) void scan1_k(const int* __restrict__ cnt,
                                                int* __restrict__ deg,
                                                int* __restrict__ bsum) {
  __shared__ int s[SCAN_BS];
  const int idx = blockIdx.x * SCAN_BS + threadIdx.x;
  int d = 0;
  if (idx < NN) {
#pragma unroll 13
    for (int r = 0; r < RR; ++r) d += cnt[r * NN + idx];  // coalesced per instr
    deg[idx] = d;
  }
  s[threadIdx.x] = d;
  __syncthreads();
  for (int off = SCAN_BS / 2; off > 0; off >>= 1) {
    if (threadIdx.x < off) s[threadIdx.x] += s[threadIdx.x + off];
    __syncthreads();
  }
  if (threadIdx.x == 0) bsum[blockIdx.x] = s[0];
}

__global__ __launch_bounds__(64) void scan2_k(int* __restrict__ bsum) {
  if (threadIdx.x == 0) {
    int run = 0;
    for (int b = 0; b < SCAN_NB; ++b) { const int v = bsum[b]; bsum[b] = run; run += v; }
  }
}

__global__ __launch_bounds__(1024) void scan3_k(const int* __restrict__ deg,
                                                const int* __restrict__ bsum,
                                                int* __restrict__ rowptr,
                                                int* __restrict__ poscur) {
  __shared__ int s[SCAN_BS];
  const int t = threadIdx.x;
  const int idx = blockIdx.x * SCAN_BS + t;
  const int v = (idx < NN) ? deg[idx] : 0;
  s[t] = v;
  __syncthreads();
  for (int off = 1; off < SCAN_BS; off <<= 1) {  // Hillis-Steele inclusive
    const int u = (t >= off) ? s[t - off] : 0;
    __syncthreads();
    s[t] += u;
    __syncthreads();
  }
  const int excl = bsum[blockIdx.x] + s[t] - v;
  if (idx < NN) { rowptr[idx] = excl; poscur[idx] = excl; }
  if (idx == NN - 1) rowptr[NN] = EE;
}

// ---- parallel type-scan: per-relation prefix over sort blocks (65 blocks) ----

__global__ __launch_bounds__(512) void scan_rel_k(const int* __restrict__ bhist,
                                                  int* __restrict__ boffrel,
                                                  int* __restrict__ total) {
  __shared__ int s[512];
  const int r = blockIdx.x;          // relation
  const int t = threadIdx.x;         // sort block
  const int v = (t < NSB) ? bhist[t * RR + r] : 0;
  s[t] = v;
  __syncthreads();
  for (int off = 1; off < 512; off <<= 1) {  // Hillis-Steele inclusive
    const int u = (t >= off) ? s[t - off] : 0;
    __syncthreads();
    s[t] += u;
    __syncthreads();
  }
  if (t < NSB) boffrel[t * RR + r] = s[t] - v;   // exclusive within relation
  if (t == 511) total[r] = s[511];
}

// 1 tiny block: scan 65 totals -> tptr (global) + chunk descriptors.
__global__ __launch_bounds__(128) void scan_tot_k(const int* __restrict__ total,
                                                  int* __restrict__ tptrg,
                                                  int4* __restrict__ chunkArr,
                                                  int* __restrict__ nchunks) {
  __shared__ int tptr[RR + 1], chbase[RR + 1];
  const int t = threadIdx.x;
  if (t == 0) {
    int run = 0, crun = 0;
    for (int r = 0; r < RR; ++r) {
      tptr[r] = run;    run  += total[r];
      chbase[r] = crun; crun += (total[r] + CHUNK - 1) / CHUNK;
    }
    tptr[RR] = run; chbase[RR] = crun;
    *nchunks = crun;
  }
  __syncthreads();
  if (t < RR) {
    tptrg[t] = tptr[t];
    const int tot = total[t];
    const int nc = (tot + CHUNK - 1) / CHUNK;
    for (int i = 0; i < nc; ++i) {
      const int beg = tptr[t] + i * CHUNK;
      chunkArr[chbase[t] + i] = make_int4(beg, min(beg + CHUNK, tptr[t] + tot), t, 0);
    }
  }
}

__global__ __launch_bounds__(512) void scatter_k(const int* __restrict__ src,
                                                 const int* __restrict__ dst,
                                                 const int* __restrict__ et,
                                                 const int* __restrict__ cnt,
                                                 const int* __restrict__ boffrel,
                                                 const int* __restrict__ tptrg,
                                                 int* __restrict__ poscur,
                                                 int* __restrict__ osrc,
                                                 int* __restrict__ opos,
                                                 float* __restrict__ oscale, int E) {
  __shared__ int cur[RR];
  if (threadIdx.x < RR)
    cur[threadIdx.x] = tptrg[threadIdx.x] + boffrel[blockIdx.x * RR + threadIdx.x];
  __syncthreads();
  const int base = blockIdx.x * SORT_BS;
#pragma unroll
  for (int it = 0; it < SORT_BS / 512; ++it) {
    const int e = base + it * 512 + threadIdx.x;
    if (e < E) {
      const int s = src[e], d = dst[e], r = et[e];
      const int q = atomicAdd(&cur[r], 1);       // LDS atomic, block-local
      const int p = atomicAdd(&poscur[d], 1);    // global, ~12 avg contention
      osrc[q] = s;
      opos[q] = p;
      oscale[q] = 1.0f / (float)cnt[r * NN + d];
    }
  }
}

// ---------------- W conversion (once, both layers) ----------------

// W[l][r][k][c] f32 -> WT[l*R+r][c][k] bf16 (transposed).
__global__ __launch_bounds__(256) void cvtw_k(const float* __restrict__ W,
                                              unsigned short* __restrict__ WT) {
  const int tid = blockIdx.x * 256 + threadIdx.x;     // one float4 per thread
  const int total4 = 2 * RR * DIM * DIM / 4;          // 133120
  if (tid >= total4) return;
  const int base = tid * 4;
  const int mat = base >> 12;
  const int rem = base & 4095;
  const int k = rem >> 6, c0 = rem & 63;
  const float4 v = *reinterpret_cast<const float4*>(W + base);
  unsigned short* o = WT + (size_t)mat * 4096;
  o[(c0 + 0) * 64 + k] = f2bf(v.x);
  o[(c0 + 1) * 64 + k] = f2bf(v.y);
  o[(c0 + 2) * 64 + k] = f2bf(v.z);
  o[(c0 + 3) * 64 + k] = f2bf(v.w);
}

// ---------------- per-layer kernels ----------------

// MFMA message kernel: one block per 256-edge relation-chunk, 4 waves x 64 edges.
__global__ __launch_bounds__(256) void msgm_k(const unsigned short* __restrict__ hbf,
                                              const int* __restrict__ osrc,
                                              const int* __restrict__ opos,
                                              const float* __restrict__ oscale,
                                              const unsigned short* __restrict__ WT,
                                              const int4* __restrict__ chunkArr,
                                              const int* __restrict__ nchunks,
                                              unsigned short* __restrict__ m) {
  const int ci = blockIdx.x;
  if (ci >= *nchunks) return;
  const int4 c = chunkArr[ci];
  const int beg = c.x, end = c.y, rel = c.z;

  __shared__ unsigned short Wl[DIM][72];   // +8 pad
  {
    const float4* s4 = reinterpret_cast<const float4*>(WT + (size_t)rel * 4096);
#pragma unroll
    for (int it = 0; it < 2; ++it) {
      const int seg = threadIdx.x + it * 256;   // 512 x 16B segments
      const int row = seg >> 3, s8 = seg & 7;
      *reinterpret_cast<float4*>(&Wl[row][s8 * 8]) = s4[seg];
    }
  }
  __syncthreads();

  const int w  = threadIdx.x >> 6;
  const int l  = threadIdx.x & 63;
  const int lr = l & 15, lq = l >> 4;

  const int ebase = beg + w * 64;
  if (ebase >= end) return;                // no barriers after this point

  short8v a[4][2];
#pragma unroll
  for (int ct = 0; ct < 4; ++ct)
#pragma unroll
    for (int kk = 0; kk < 2; ++kk)
      a[ct][kk] = *reinterpret_cast<const short8v*>(&Wl[ct * 16 + lr][kk * 32 + lq * 8]);

  short8v b[4][2];
  int eidx[4];
#pragma unroll
  for (int et = 0; et < 4; ++et) {
    eidx[et] = ebase + et * 16 + lr;
    const int e = min(eidx[et], end - 1);  // clamp (safe dup, store guarded)
    const int s = osrc[e];
    const unsigned short* hp = hbf + (size_t)s * DIM;
    b[et][0] = *reinterpret_cast<const short8v*>(hp + lq * 8);
    b[et][1] = *reinterpret_cast<const short8v*>(hp + 32 + lq * 8);
  }

  floatx4 acc[4][4];
#pragma unroll
  for (int ct = 0; ct < 4; ++ct)
#pragma unroll
    for (int et = 0; et < 4; ++et)
      acc[ct][et] = (floatx4){0.f, 0.f, 0.f, 0.f};

#pragma unroll
  for (int kk = 0; kk < 2; ++kk)
#pragma unroll
    for (int ct = 0; ct < 4; ++ct)
#pragma unroll
      for (int et = 0; et < 4; ++et)
        acc[ct][et] = __builtin_amdgcn_mfma_f32_16x16x32_bf16(a[ct][kk], b[et][kk],
                                                              acc[ct][et], 0, 0, 0);

#pragma unroll
  for (int et = 0; et < 4; ++et) {
    const int e = eidx[et];
    if (e < end) {
      const float sc = oscale[e];
      unsigned short* op = m + (size_t)opos[e] * DIM;
#pragma unroll
      for (int ct = 0; ct < 4; ++ct) {
        ushort4 o;
        o.x = f2bf(acc[ct][et][0] * sc);
        o.y = f2bf(acc[ct][et][1] * sc);
        o.z = f2bf(acc[ct][et][2] * sc);
        o.w = f2bf(acc[ct][et][3] * sc);
        *reinterpret_cast<ushort4*>(op + ct * 16 + lq * 4) = o;
      }
    }
  }
}

// Dense node transform: rt = h@root + b, rs = relu(h@rw + rb); also emits h as bf16.
__global__ __launch_bounds__(256) void xform_k(const float* __restrict__ h,
                                               const float* __restrict__ root,
                                               const float* __restrict__ bias,
                                               const float* __restrict__ rw,
                                               const float* __restrict__ rb,
                                               float* __restrict__ rt,
                                               float* __restrict__ rs,
                                               unsigned short* __restrict__ hbf, int N) {
  __shared__ float Wl0[DIM * DIM];
  __shared__ float Wl1[DIM * DIM];
  __shared__ float xs[XNB][68];
#pragma unroll
  for (int i = 0; i < 4; ++i) {
    reinterpret_cast<float4*>(Wl0)[threadIdx.x + i * 256] =
        reinterpret_cast<const float4*>(root)[threadIdx.x + i * 256];
    reinterpret_cast<float4*>(Wl1)[threadIdx.x + i * 256] =
        reinterpret_cast<const float4*>(rw)[threadIdx.x + i * 256];
  }

  const int g = threadIdx.x >> 4, li = threadIdx.x & 15;
  const int base = blockIdx.x * XNB;
#pragma unroll
  for (int r = 0; r < 4; ++r) {
    const int n = base + g * 4 + r;
    float4 v = make_float4(0.f, 0.f, 0.f, 0.f);
    if (n < N) v = *reinterpret_cast<const float4*>(h + (size_t)n * DIM + li * 4);
    *reinterpret_cast<float4*>(&xs[g * 4 + r][li * 4]) = v;
  }
  __syncthreads();

  if (hbf != nullptr) {
#pragma unroll
    for (int r = 0; r < 4; ++r) {
      const int n = base + g * 4 + r;
      if (n < N) {
        const float4 v = *reinterpret_cast<const float4*>(&xs[g * 4 + r][li * 4]);
        ushort4 o;
        o.x = f2bf(v.x); o.y = f2bf(v.y); o.z = f2bf(v.z); o.w = f2bf(v.w);
        *reinterpret_cast<ushort4*>(hbf + (size_t)n * DIM + li * 4) = o;
      }
    }
  }

  float aR[4][4], aS[4][4];
#pragma unroll
  for (int r = 0; r < 4; ++r)
#pragma unroll
    for (int q = 0; q < 4; ++q) { aR[r][q] = 0.f; aS[r][q] = 0.f; }

#pragma unroll 4
  for (int k = 0; k < DIM; ++k) {
    const float4 wr = *reinterpret_cast<const float4*>(&Wl0[k * DIM + li * 4]);
    const float4 wv = *reinterpret_cast<const float4*>(&Wl1[k * DIM + li * 4]);
#pragma unroll
    for (int r = 0; r < 4; ++r) {
      const float xv = xs[g * 4 + r][k];
      aR[r][0] += xv * wr.x; aR[r][1] += xv * wr.y; aR[r][2] += xv * wr.z; aR[r][3] += xv * wr.w;
      aS[r][0] += xv * wv.x; aS[r][1] += xv * wv.y; aS[r][2] += xv * wv.z; aS[r][3] += xv * wv.w;
    }
  }

  const float4 bv = reinterpret_cast<const float4*>(bias)[li];
  const float4 cv = reinterpret_cast<const float4*>(rb)[li];
#pragma unroll
  for (int r = 0; r < 4; ++r) {
    const int n = base + g * 4 + r;
    if (n < N) {
      *reinterpret_cast<float4*>(rt + (size_t)n * DIM + li * 4) =
          make_float4(aR[r][0] + bv.x, aR[r][1] + bv.y, aR[r][2] + bv.z, aR[r][3] + bv.w);
      *reinterpret_cast<float4*>(rs + (size_t)n * DIM + li * 4) =
          make_float4(fmaxf(aS[r][0] + cv.x, 0.f), fmaxf(aS[r][1] + cv.y, 0.f),
                      fmaxf(aS[r][2] + cv.z, 0.f), fmaxf(aS[r][3] + cv.w, 0.f));
    }
  }
}

// Streaming epilogue: hout = relu(sum(msgs) + rt) + rs. Msg loop unrolled 4x.
__global__ __launch_bounds__(256) void gather2_k(const unsigned short* __restrict__ m,
                                                 const int* __restrict__ rowptr,
                                                 const float* __restrict__ rt,
                                                 const float* __restrict__ rs,
                                                 float* __restrict__ hout, int N) {
  const int g = threadIdx.x >> 4, li = threadIdx.x & 15;
  const int n = blockIdx.x * 16 + g;
  if (n >= N) return;

  float a0 = 0.f, a1 = 0.f, a2 = 0.f, a3 = 0.f;
  const int jb = rowptr[n], je = rowptr[n + 1];
  int j = jb;
  for (; j + 4 <= je; j += 4) {
    const ushort4 v0 = *reinterpret_cast<const ushort4*>(m + (size_t)(j + 0) * DIM + li * 4);
    const ushort4 v1 = *reinterpret_cast<const ushort4*>(m + (size_t)(j + 1) * DIM + li * 4);
    const ushort4 v2 = *reinterpret_cast<const ushort4*>(m + (size_t)(j + 2) * DIM + li * 4);
    const ushort4 v3 = *reinterpret_cast<const ushort4*>(m + (size_t)(j + 3) * DIM + li * 4);
    a0 += bf2f(v0.x) + bf2f(v1.x) + bf2f(v2.x) + bf2f(v3.x);
    a1 += bf2f(v0.y) + bf2f(v1.y) + bf2f(v2.y) + bf2f(v3.y);
    a2 += bf2f(v0.z) + bf2f(v1.z) + bf2f(v2.z) + bf2f(v3.z);
    a3 += bf2f(v0.w) + bf2f(v1.w) + bf2f(v2.w) + bf2f(v3.w);
  }
  for (; j < je; ++j) {
    const ushort4 v = *reinterpret_cast<const ushort4*>(m + (size_t)j * DIM + li * 4);
    a0 += bf2f(v.x); a1 += bf2f(v.y); a2 += bf2f(v.z); a3 += bf2f(v.w);
  }

  const float4 t = *reinterpret_cast<const float4*>(rt + (size_t)n * DIM + li * 4);
  const float4 s = *reinterpret_cast<const float4*>(rs + (size_t)n * DIM + li * 4);
  *reinterpret_cast<float4*>(hout + (size_t)n * DIM + li * 4) =
      make_float4(fmaxf(a0 + t.x, 0.f) + s.x, fmaxf(a1 + t.y, 0.f) + s.y,
                  fmaxf(a2 + t.z, 0.f) + s.z, fmaxf(a3 + t.w, 0.f) + s.w);
}

// ---------------- last-resort fallback (float atomics, self-contained) ----------------

__global__ __launch_bounds__(256) void count_k(const int* __restrict__ dst,
                                               const int* __restrict__ et,
                                               int* __restrict__ cnt, int E) {
  int e = blockIdx.x * 256 + threadIdx.x;
  if (e < E) atomicAdd(&cnt[dst[e] * RR + et[e]], 1);
}

__global__ __launch_bounds__(256) void edge_k(const float* __restrict__ h,
                                              const int* __restrict__ src,
                                              const int* __restrict__ dst,
                                              const int* __restrict__ et,
                                              const float* __restrict__ W,
                                              const int* __restrict__ cnt,
                                              float* __restrict__ accum, int E) {
  __shared__ float xs[16][68];
  const int g = threadIdx.x >> 4, li = threadIdx.x & 15;
  const int e = blockIdx.x * 16 + g;
  if (e >= E) return;
  const int s = src[e], d = dst[e], t = et[e];
  *reinterpret_cast<float4*>(&xs[g][li * 4]) =
      *reinterpret_cast<const float4*>(h + (size_t)s * DIM + li * 4);
  const float* Wt = W + (size_t)t * (DIM * DIM) + li * 4;
  float a0 = 0.f, a1 = 0.f, a2 = 0.f, a3 = 0.f;
#pragma unroll 8
  for (int k = 0; k < DIM; ++k) {
    const float xd = xs[g][k];
    const float4 w = *reinterpret_cast<const float4*>(Wt + k * DIM);
    a0 += xd * w.x; a1 += xd * w.y; a2 += xd * w.z; a3 += xd * w.w;
  }
  const float sc = 1.0f / (float)cnt[d * RR + t];
  float* o = accum + (size_t)d * DIM + li * 4;
  unsafeAtomicAdd(o + 0, a0 * sc);
  unsafeAtomicAdd(o + 1, a1 * sc);
  unsafeAtomicAdd(o + 2, a2 * sc);
  unsafeAtomicAdd(o + 3, a3 * sc);
}

__global__ __launch_bounds__(256) void node_k(const float* __restrict__ h,
                                              const float* __restrict__ root,
                                              const float* __restrict__ bias,
                                              const float* __restrict__ rw,
                                              const float* __restrict__ rb,
                                              float* __restrict__ io, int N) {
  __shared__ float xs[16][68];
  const int g = threadIdx.x >> 4, li = threadIdx.x & 15;
  const int n = blockIdx.x * 16 + g;
  if (n >= N) return;
  *reinterpret_cast<float4*>(&xs[g][li * 4]) =
      *reinterpret_cast<const float4*>(h + (size_t)n * DIM + li * 4);
  float r0 = 0.f, r1 = 0.f, r2 = 0.f, r3 = 0.f;
  float s0 = 0.f, s1 = 0.f, s2 = 0.f, s3 = 0.f;
#pragma unroll 8
  for (int k = 0; k < DIM; ++k) {
    const float hd = xs[g][k];
    const float4 w = *reinterpret_cast<const float4*>(root + k * DIM + li * 4);
    const float4 v = *reinterpret_cast<const float4*>(rw + k * DIM + li * 4);
    r0 += hd * w.x; r1 += hd * w.y; r2 += hd * w.z; r3 += hd * w.w;
    s0 += hd * v.x; s1 += hd * v.y; s2 += hd * v.z; s3 += hd * v.w;
  }
  float* o = io + (size_t)n * DIM + li * 4;
  const float4 acc = *reinterpret_cast<const float4*>(o);
  const float4 b = *reinterpret_cast<const float4*>(bias + li * 4);
  const float4 c = *reinterpret_cast<const float4*>(rb + li * 4);
  float o0 = fmaxf(acc.x + r0 + b.x, 0.f) + fmaxf(s0 + c.x, 0.f);
  float o1 = fmaxf(acc.y + r1 + b.y, 0.f) + fmaxf(s1 + c.y, 0.f);
  float o2 = fmaxf(acc.z + r2 + b.z, 0.f) + fmaxf(s2 + c.z, 0.f);
  float o3 = fmaxf(acc.w + r3 + b.w, 0.f) + fmaxf(s3 + c.w, 0.f);
  *reinterpret_cast<float4*>(o) = make_float4(o0, o1, o2, o3);
}

// ---------------- host ----------------

extern "C" void kernel_launch(void* const* d_in, const int* in_sizes, int n_in,
                              void* d_out, int out_size, void* d_ws, size_t ws_size,
                              hipStream_t stream) {
  const float* x    = (const float*)d_in[0];
  const int*   ei   = (const int*)d_in[1];
  const int*   et   = (const int*)d_in[2];
  const float* W    = (const float*)d_in[3];
  const float* root = (const float*)d_in[4];
  const float* bias = (const float*)d_in[5];
  const float* resW = (const float*)d_in[6];
  const float* resb = (const float*)d_in[7];
  float* out = (float*)d_out;

  const int* src = ei;
  const int* dstp = ei + EE;

  char* ws = (char*)d_ws;
  size_t off = 0;
  auto take = [&](size_t bytes) -> void* {
    void* p = ws + off;
    off = (off + bytes + 255) & ~(size_t)255;
    return p;
  };
  unsigned short* m = (unsigned short*)take((size_t)EE * DIM * sizeof(unsigned short));
  float* h1      = (float*)take((size_t)NN * DIM * sizeof(float));
  int* deg       = (int*)take((size_t)NN * sizeof(int));
  int* rowptr    = (int*)take((size_t)(NN + 1) * sizeof(int));
  int* poscur    = (int*)take((size_t)NN * sizeof(int));
  int* bhist     = (int*)take((size_t)NSB * RR * sizeof(int));
  int* boffrel   = (int*)take((size_t)NSB * RR * sizeof(int));
  int* total     = (int*)take((size_t)RR * sizeof(int));
  int* tptrg     = (int*)take((size_t)RR * sizeof(int));
  int* bsum      = (int*)take((size_t)SCAN_NB * sizeof(int));
  int* osrc      = (int*)take((size_t)EE * sizeof(int));
  int* opos      = (int*)take((size_t)EE * sizeof(int));
  float* oscale  = (float*)take((size_t)EE * sizeof(float));
  int4* chunkArr = (int4*)take((size_t)MAXCHUNKS * sizeof(int4));
  int* nchunks   = (int*)take(256);
  float* rt      = (float*)take((size_t)NN * DIM * sizeof(float));
  float* rs      = (float*)take((size_t)NN * DIM * sizeof(float));
  unsigned short* hbf = (unsigned short*)take((size_t)NN * DIM * sizeof(unsigned short));
  unsigned short* wbt = (unsigned short*)take((size_t)2 * RR * DIM * DIM * sizeof(unsigned short));
  const size_t main_off = off;
  int* cnt       = (int*)m;  // alias ([R][N] layout, 13MB): dead once msgm writes m

  if (main_off <= ws_size) {
    // ---- sorted MFMA path (no rocclr fills) ----
    zero4_k<<<(NN * RR / 4 + 255) / 256, 256, 0, stream>>>((int4*)cnt, NN * RR / 4);
    cnt_k<<<(EE + 511) / 512, 512, 0, stream>>>(dstp, et, cnt, EE);
    bhist_k<<<NSB, 512, 0, stream>>>(et, bhist, EE);
    scan1_k<<<SCAN_NB, 1024, 0, stream>>>(cnt, deg, bsum);
    scan2_k<<<1, 64, 0, stream>>>(bsum);
    scan3_k<<<SCAN_NB, 1024, 0, stream>>>(deg, bsum, rowptr, poscur);
    scan_rel_k<<<RR, 512, 0, stream>>>(bhist, boffrel, total);
    scan_tot_k<<<1, 128, 0, stream>>>(total, tptrg, chunkArr, nchunks);
    scatter_k<<<NSB, 512, 0, stream>>>(src, dstp, et, cnt, boffrel, tptrg, poscur,
                                       osrc, opos, oscale, EE);
    cvtw_k<<<(2 * RR * DIM * DIM / 4 + 255) / 256, 256, 0, stream>>>(W, wbt);

    const int XG = (NN + XNB - 1) / XNB;
    // layer 0: x -> h1
    xform_k<<<XG, 256, 0, stream>>>(x, root, bias, resW, resb, rt, rs, hbf, NN);
    msgm_k<<<MAXCHUNKS, 256, 0, stream>>>(hbf, osrc, opos, oscale, wbt, chunkArr, nchunks, m);
    gather2_k<<<(NN + 15) / 16, 256, 0, stream>>>(m, rowptr, rt, rs, h1, NN);
    // layer 1: h1 -> out
    xform_k<<<XG, 256, 0, stream>>>(h1, root + DIM * DIM, bias + DIM,
                                    resW + DIM * DIM, resb + DIM, rt, rs, hbf, NN);
    msgm_k<<<MAXCHUNKS, 256, 0, stream>>>(hbf, osrc, opos, oscale,
                                          wbt + (size_t)RR * DIM * DIM, chunkArr, nchunks, m);
    gather2_k<<<(NN + 15) / 16, 256, 0, stream>>>(m, rowptr, rt, rs, out, NN);
  } else {
    // ---- fallback: atomic path (needs only 25.8 MB) ----
    int* fcnt = (int*)ws;
    float* fh1 = (float*)(ws + (size_t)NN * RR * sizeof(int));
    hipMemsetAsync(fcnt, 0, (size_t)NN * RR * sizeof(int), stream);
    hipMemsetAsync(fh1, 0, (size_t)NN * DIM * sizeof(float), stream);
    hipMemsetAsync(out, 0, (size_t)NN * DIM * sizeof(float), stream);
    count_k<<<(EE + 255) / 256, 256, 0, stream>>>(dstp, et, fcnt, EE);
    edge_k<<<(EE + 15) / 16, 256, 0, stream>>>(x, src, dstp, et, W, fcnt, fh1, EE);
    node_k<<<(NN + 15) / 16, 256, 0, stream>>>(x, root, bias, resW, resb, fh1, NN);
    edge_k<<<(EE + 15) / 16, 256, 0, stream>>>(fh1, src, dstp, et,
                                               W + (size_t)RR * DIM * DIM, fcnt, out, EE);
    node_k<<<(NN + 15) / 16, 256, 0, stream>>>(fh1, root + DIM * DIM, bias + DIM,
                                               resW + DIM * DIM, resb + DIM, out, NN);
  }
}